// Round 5
// baseline (87.524 us; speedup 1.0000x reference)
//
#include <hip/hip_runtime.h>

// AttnMap restructure (verified rounds 1-4):
//   Mt[bt][f][ch] = sum_q dec[b, q*16+t, ch] * W[q*8 + (ch>>5)][f]
//   out[bt][s][f] = relu( sum_ch enc[bt][s][ch] * Mt[f][ch] + bias[f] )
// Round 5: barrier-free streaming GEMM + register double-buffered A-stream
// (half-chunk pipeline). B-slice (64f x 256k) lives in AGPRs; no LDS.

#define CCH  256
#define FF   256
#define HW   1024

typedef __bf16 bf16x8 __attribute__((ext_vector_type(8)));
typedef float  f32x4  __attribute__((ext_vector_type(4)));
typedef unsigned short u16x8 __attribute__((ext_vector_type(8)));

__device__ __forceinline__ unsigned short f2bf(float f) {
    __bf16 b = (__bf16)f;
    return __builtin_bit_cast(unsigned short, b);
}

// ---------------- Phase 1: Mt[bt][f][ch] (bf16, f-major) ----------------
__global__ __launch_bounds__(256) void compute_Mt_kernel(
        const float* __restrict__ dec, const float* __restrict__ W,
        unsigned short* __restrict__ Mt) {
    const int j  = blockIdx.x;            // g-pair: g = 2j, 2j+1
    const int bt = blockIdx.y;
    const int b  = bt >> 4, t = bt & 15;
    const int f  = threadIdx.x;
    __shared__ float ldec[16][64];        // 16 q x 64 ch (this g-pair)

    const float* decbt = dec + (size_t)b * 65536 + (size_t)t * 256 + j * 64;
    {
        const int q = threadIdx.x >> 4, seg = threadIdx.x & 15;
        const float4 v = *reinterpret_cast<const float4*>(decbt + q * 4096 + seg * 4);
        *reinterpret_cast<float4*>(&ldec[q][seg * 4]) = v;
    }
    __syncthreads();

    u16x8 rv[8];
    #pragma unroll
    for (int gi = 0; gi < 2; ++gi) {
        const int g = j * 2 + gi;
        float wv[16];
        #pragma unroll
        for (int q = 0; q < 16; ++q) wv[q] = W[(q * 8 + g) * FF + f];   // coalesced
        #pragma unroll
        for (int cc = 0; cc < 32; ++cc) {
            float s = 0.f;
            #pragma unroll
            for (int q = 0; q < 16; ++q) s += ldec[q][gi * 32 + cc] * wv[q];
            const int idx = gi * 32 + cc;
            rv[idx >> 3][idx & 7] = f2bf(s);
        }
    }
    unsigned short* dst = Mt + (size_t)bt * (FF * CCH) + (size_t)f * CCH + j * 64;
    #pragma unroll
    for (int s = 0; s < 8; ++s)
        *reinterpret_cast<u16x8*>(dst + s * 8) = rv[s];   // 128 B/thread contiguous
}

// ---------------- Phase 2: streaming MFMA GEMM, half-chunk pipelined ----------------
// 2048 blocks x 64 threads. Wave -> (bt, rq, fq): 256 rows x 64 f.
// Per lane A half-buffer: 8 f32x4 (rows r0+lr, k-half of 128).
__device__ __forceinline__ void loadA(const float* ap, f32x4* A) {
    #pragma unroll
    for (int kk = 0; kk < 4; ++kk) {
        A[2 * kk]     = *reinterpret_cast<const f32x4*>(ap + kk * 32);
        A[2 * kk + 1] = *reinterpret_cast<const f32x4*>(ap + kk * 32 + 4);
    }
}

__device__ __forceinline__ void computeA(const f32x4* A, const bf16x8 Bf[4][8],
                                         int kbase, f32x4* acc) {
    #pragma unroll
    for (int kk = 0; kk < 4; ++kk) {
        bf16x8 a8;
        #pragma unroll
        for (int jj = 0; jj < 4; ++jj) {
            a8[jj]     = (__bf16)A[2 * kk][jj];
            a8[4 + jj] = (__bf16)A[2 * kk + 1][jj];
        }
        #pragma unroll
        for (int fn = 0; fn < 4; ++fn)
            acc[fn] = __builtin_amdgcn_mfma_f32_16x16x32_bf16(
                a8, Bf[fn][kbase + kk], acc[fn], 0, 0, 0);
    }
}

__global__ __launch_bounds__(64, 2) void gemm_stream_kernel(
        const float* __restrict__ E, const unsigned short* __restrict__ Mt,
        const float* __restrict__ bias, float* __restrict__ O) {
    const int id0 = blockIdx.x;                       // 0..2047
    const int id  = ((id0 & 7) << 8) | (id0 >> 3);    // XCD-chunked bijection
    const int bt = id >> 4;
    const int rq = (id >> 2) & 3;                     // row quarter (256 rows)
    const int fq = id & 3;                            // f quarter (64 f)
    const int lane = threadIdx.x;
    const int lr = lane & 15;                         // row / f within 16
    const int lg = lane >> 4;                         // k-group 0..3

    const float*          Ebt = E  + (size_t)bt * (HW * CCH);
    const unsigned short* Mtb = Mt + (size_t)bt * (FF * CCH) + (size_t)(fq * 64) * CCH;
    float*                Obt = O  + (size_t)bt * (HW * FF);

    // ---- B-slice into registers/AGPRs (once) ----
    bf16x8 Bf[4][8];
    #pragma unroll
    for (int fn = 0; fn < 4; ++fn) {
        const unsigned short* bp = Mtb + (size_t)(fn * 16 + lr) * CCH + lg * 8;
        #pragma unroll
        for (int kk = 0; kk < 8; ++kk)
            Bf[fn][kk] = *reinterpret_cast<const bf16x8*>(bp + kk * 32);
    }
    float bv[4];
    #pragma unroll
    for (int fn = 0; fn < 4; ++fn) bv[fn] = bias[fq * 64 + fn * 16 + lr];

    // lane base for A: row (rq*256 + c*16 + lr), k-offset lg*8
    const float* abase = Ebt + (size_t)(rq * 256 + lr) * CCH + lg * 8;

    f32x4 A0[8], A1[8];                 // named half-buffers (static indexing only)
    loadA(abase, A0);                   // chunk 0, half 0

    for (int c = 0; c < 16; ++c) {
        const float* ap = abase + (size_t)c * 16 * CCH;
        loadA(ap + 128, A1);            // this chunk, half 1 (in flight over computeA(A0))
        f32x4 acc[4];
        #pragma unroll
        for (int fn = 0; fn < 4; ++fn) acc[fn] = (f32x4)0.f;
        computeA(A0, Bf, 0, acc);
        if (c < 15)
            loadA(ap + 16 * CCH, A0);   // next chunk, half 0 (in flight over computeA(A1))
        computeA(A1, Bf, 4, acc);

        const int r0 = rq * 256 + c * 16;
        #pragma unroll
        for (int fn = 0; fn < 4; ++fn) {
            #pragma unroll
            for (int r = 0; r < 4; ++r) {
                const int row = r0 + lg * 4 + r;
                const float v = fmaxf(acc[fn][r] + bv[fn], 0.f);
                __builtin_nontemporal_store(
                    v, Obt + (size_t)row * FF + fq * 64 + fn * 16 + lr);
            }
        }
    }
}

extern "C" void kernel_launch(void* const* d_in, const int* in_sizes, int n_in,
                              void* d_out, int out_size, void* d_ws, size_t ws_size,
                              hipStream_t stream) {
    const float* dec  = (const float*)d_in[0];   // (8, 256, 256)
    const float* enc  = (const float*)d_in[1];   // (8, 16, 32, 32, 256)
    const float* W    = (const float*)d_in[2];   // (128, 256)
    const float* bias = (const float*)d_in[3];   // (256,)
    float* out = (float*)d_out;                  // (8, 16, 32, 32, 256) fp32
    unsigned short* Mt = (unsigned short*)d_ws;  // 128*256*256*2 = 16.8 MB bf16

    compute_Mt_kernel<<<dim3(4, 128), dim3(256), 0, stream>>>(dec, W, Mt);
    gemm_stream_kernel<<<dim3(2048), dim3(64), 0, stream>>>(enc, Mt, bias, out);
}